// Round 7
// baseline (628.201 us; speedup 1.0000x reference)
//
#include <hip/hip_runtime.h>
#include <hip/hip_bf16.h>

typedef unsigned short u16;
typedef unsigned int   u32;
typedef _Float16 half8 __attribute__((ext_vector_type(8)));
typedef __attribute__((ext_vector_type(16))) float f32x16;

constexpr int NB = 4;        // batch
constexpr int S  = 4096;     // sequence
constexpr int D  = 1024;     // model dim
constexpr int BK = 64;       // GEMM K-tile (4 x K=16 mfma steps per barrier)

__device__ __forceinline__ u16 h2u(_Float16 h) {
    union { _Float16 h; u16 u; } v; v.h = h; return v.u;
}

// Async global->LDS, 16 B per lane. LDS destination is wave-uniform
// base + lane*16 (lane-linear chunk order).
__device__ __forceinline__ void async16(const void* g, void* l) {
    __builtin_amdgcn_global_load_lds(
        (const __attribute__((address_space(1))) unsigned int*)g,
        (__attribute__((address_space(3))) unsigned int*)l, 16, 0, 0);
}

// ---------------------------------------------------------------------------
// NT GEMM core, mfma_f32_32x32x16_f16 version: A [128 x K] fp16 row-major
// (pre-offset), B [128 x K] fp16 row-major (pre-offset). 128x128 tile,
// 256 threads = 4 waves (2x2); each wave 64x64 = 2x2 mfma-32 tiles.
// Per barrier-pair: 16 ds_read_b128 + 16 MFMA per wave (vs 32 MFMA with the
// 16x16 shape) -- same FLOP, half the MFMA issue slots.
//
// LDS: 128 rows x 8 chunks of 16B, XOR swizzle chunk = gc ^ (row&7); swizzle
// applied on the staging SOURCE address (global_load_lds is lane-linear).
// Fragment layouts (guide §3, HW-verified, dtype-independent):
//   A: lane holds A[m=lane&31][kk*16 + (lane>>5)*8 + j]
//   B: lane holds B[n=lane&31][kk*16 + (lane>>5)*8 + j]
//   C: acc[r] = C[row=(r&3)+8*(r>>2)+4*(lane>>5)][col=lane&31]
// ---------------------------------------------------------------------------
__device__ __forceinline__ void gemm_nt_async(
    const u16* __restrict__ A, const u16* __restrict__ B, int K,
    u16* As, u16* Bs, f32x16 acc[2][2])
{
    const int tid   = threadIdx.x;
    const int lane  = tid & 63;
    const int wid   = tid >> 6;
    const int l31   = lane & 31;
    const int khalf = lane >> 5;               // 0/1 -> k-offset 0/8
    const int ph    = l31 & 7;                 // row bank phase
    const int wm    = (wid & 1) * 64;
    const int wn    = (wid >> 1) * 64;

    // --- staging addressing (swizzled source, lane-linear LDS dest) ---
    const int rl = lane >> 3;                  // 0..7 row within 8-row group
    const int cl = lane & 7;                   // 0..7 LDS chunk position
    const int gc = cl ^ rl;                    // swizzled global chunk
    const int row0 = wid * 32 + rl;            // instr j adds 8 rows
    const u16* Ag = A + (size_t)row0 * K + gc * 8;
    const u16* Bg = B + (size_t)row0 * K + gc * 8;
    u16* Al = As + ((size_t)wid * 256 + lane) * 8;
    u16* Bl = Bs + ((size_t)wid * 256 + lane) * 8;

    for (int k0 = 0; k0 < K; k0 += BK) {
        __syncthreads();                       // prev iter's LDS reads done
#pragma unroll
        for (int j = 0; j < 4; ++j)
            async16(Ag + k0 + (size_t)j * 8 * K, Al + j * 512);
#pragma unroll
        for (int j = 0; j < 4; ++j)
            async16(Bg + k0 + (size_t)j * 8 * K, Bl + j * 512);
        __syncthreads();                       // vmcnt(0) drain -> data in LDS
#pragma unroll
        for (int kk = 0; kk < 4; ++kk) {
            const int c = ((kk * 2 + khalf) ^ ph) * 8;
            half8 a0 = *(const half8*)(As + (wm      + l31) * 64 + c);
            half8 a1 = *(const half8*)(As + (wm + 32 + l31) * 64 + c);
            half8 b0 = *(const half8*)(Bs + (wn      + l31) * 64 + c);
            half8 b1 = *(const half8*)(Bs + (wn + 32 + l31) * 64 + c);
            acc[0][0] = __builtin_amdgcn_mfma_f32_32x32x16_f16(a0, b0, acc[0][0], 0, 0, 0);
            acc[0][1] = __builtin_amdgcn_mfma_f32_32x32x16_f16(a0, b1, acc[0][1], 0, 0, 0);
            acc[1][0] = __builtin_amdgcn_mfma_f32_32x32x16_f16(a1, b0, acc[1][0], 0, 0, 0);
            acc[1][1] = __builtin_amdgcn_mfma_f32_32x32x16_f16(a1, b1, acc[1][1], 0, 0, 0);
        }
    }
}

// C/D index helpers (32x32 layout)
__device__ __forceinline__ int cd_row(int r, int lane) {
    return (r & 3) + 8 * (r >> 2) + 4 * (lane >> 5);
}

// ---------------------------------------------------------------------------
// 0) fp32 -> fp16 cast, 8 elems/thread
// ---------------------------------------------------------------------------
__global__ __launch_bounds__(256) void cvt_kernel(
    const float* __restrict__ in, u16* __restrict__ out, int n8)
{
    const int i = blockIdx.x * 256 + threadIdx.x;
    if (i >= n8) return;
    const float4 a = *(const float4*)(in + (size_t)i * 8);
    const float4 b = *(const float4*)(in + (size_t)i * 8 + 4);
    half8 h;
    h[0] = (_Float16)a.x; h[1] = (_Float16)a.y;
    h[2] = (_Float16)a.z; h[3] = (_Float16)a.w;
    h[4] = (_Float16)b.x; h[5] = (_Float16)b.y;
    h[6] = (_Float16)b.z; h[7] = (_Float16)b.w;
    *(half8*)(out + (size_t)i * 8) = h;
}

// ---------------------------------------------------------------------------
// 1) QKV projection: out[s,e] = sum_d x16[s,d] * W16[e,d]  (NT, K=D)
// grid (NB*S/128=128, D/128=8, 3); z=0/1 -> Q/K linear; z=2 -> V written
// TRANSPOSED to Vt[b][e][s] via an LDS transpose epilogue (stride 136 to
// spread bank phases). Kills the separate transpose_v dispatch.
// ---------------------------------------------------------------------------
__global__ __launch_bounds__(256) void qkv_kernel(
    const u16* __restrict__ x16, const u16* __restrict__ W16,
    u16* __restrict__ Q, u16* __restrict__ Kb, u16* __restrict__ Vt)
{
    __shared__ __align__(16) u16 Sm[17408];    // 34 KB: 2x8192 staging / 128x136 transpose
    u16* As = Sm;
    u16* Bs = Sm + 8192;
    const int tile_m = blockIdx.x * 128;
    const int tile_n = blockIdx.y * 128;
    const u16* W = W16 + (size_t)blockIdx.z * D * D;

    f32x16 acc[2][2];
#pragma unroll
    for (int i = 0; i < 2; ++i)
#pragma unroll
        for (int j = 0; j < 2; ++j) acc[i][j] = (f32x16)0.0f;

    gemm_nt_async(x16 + (size_t)tile_m * D, W + (size_t)tile_n * D, D, As, Bs, acc);

    const int tid = threadIdx.x, lane = tid & 63, wid = tid >> 6;
    const int l31 = lane & 31;
    const int wm = (wid & 1) * 64, wn = (wid >> 1) * 64;

    if (blockIdx.z < 2) {
        u16* out = (blockIdx.z == 0) ? Q : Kb;
#pragma unroll
        for (int im = 0; im < 2; ++im)
#pragma unroll
            for (int in = 0; in < 2; ++in)
#pragma unroll
                for (int r = 0; r < 16; ++r) {
                    const int row = tile_m + wm + im * 32 + cd_row(r, lane);
                    const int col = tile_n + wn + in * 32 + l31;
                    out[(size_t)row * D + col] = h2u((_Float16)acc[im][in][r]);
                }
    } else {
        // V: transpose through LDS, write Vt[b][e][s]
        __syncthreads();                       // staging LDS reads all done
#pragma unroll
        for (int im = 0; im < 2; ++im)
#pragma unroll
            for (int in = 0; in < 2; ++in)
#pragma unroll
                for (int r = 0; r < 16; ++r) {
                    const int sl = wm + im * 32 + cd_row(r, lane);   // local s
                    const int el = wn + in * 32 + l31;               // local e
                    Sm[el * 136 + sl] = h2u((_Float16)acc[im][in][r]);
                }
        __syncthreads();
        const int b  = tile_m >> 12;
        const int s0 = tile_m & (S - 1);
#pragma unroll
        for (int it = 0; it < 8; ++it) {
            const int idx = it * 256 + tid;    // 0..2047
            const int e  = idx >> 4;           // 0..127
            const int sc = (idx & 15) * 8;     // 0..120
            half8 v = *(const half8*)(Sm + e * 136 + sc);
            *(half8*)(Vt + (size_t)b * D * S + (size_t)(tile_n + e) * S + s0 + sc) = v;
        }
    }
}

// ---------------------------------------------------------------------------
// 2) scores: P[b][q][k] = Q_b[q,:] . K_b[k,:]   (NT, K=D), grid (32,32,4)
// ---------------------------------------------------------------------------
__global__ __launch_bounds__(256) void scores_kernel(
    const u16* __restrict__ Q, const u16* __restrict__ Kb, u16* __restrict__ P)
{
    __shared__ __align__(16) u16 As[128 * BK];
    __shared__ __align__(16) u16 Bs[128 * BK];
    const int b = blockIdx.z;
    const int tile_m = blockIdx.x * 128;
    const int tile_n = blockIdx.y * 128;
    const u16* Ab = Q  + (size_t)b * S * D + (size_t)tile_m * D;
    const u16* Bv = Kb + (size_t)b * S * D + (size_t)tile_n * D;

    f32x16 acc[2][2];
#pragma unroll
    for (int i = 0; i < 2; ++i)
#pragma unroll
        for (int j = 0; j < 2; ++j) acc[i][j] = (f32x16)0.0f;

    gemm_nt_async(Ab, Bv, D, As, Bs, acc);

    u16* Pb = P + (size_t)b * S * S;
    const int tid = threadIdx.x, lane = tid & 63, wid = tid >> 6;
    const int l31 = lane & 31;
    const int wm = (wid & 1) * 64, wn = (wid >> 1) * 64;
#pragma unroll
    for (int im = 0; im < 2; ++im)
#pragma unroll
        for (int in = 0; in < 2; ++in)
#pragma unroll
            for (int r = 0; r < 16; ++r) {
                const int row = tile_m + wm + im * 32 + cd_row(r, lane);
                const int col = tile_n + wn + in * 32 + l31;
                Pb[(size_t)row * S + col] = h2u((_Float16)acc[im][in][r]);
            }
}

// ---------------------------------------------------------------------------
// 3) softmax over each row of P (4096 fp16), in place. 256 thr x 16 elems.
// ---------------------------------------------------------------------------
__global__ __launch_bounds__(256) void softmax_kernel(u16* __restrict__ P)
{
    const size_t row = blockIdx.x;                 // 0..NB*S-1 (flat: stride S)
    u16* p = P + row * S;
    const int tid = threadIdx.x;

    half8 h0 = *(const half8*)(p + tid * 16);
    half8 h1 = *(const half8*)(p + tid * 16 + 8);
    float v[16];
#pragma unroll
    for (int i = 0; i < 8; ++i) { v[i] = (float)h0[i]; v[8 + i] = (float)h1[i]; }

    float m = v[0];
#pragma unroll
    for (int i = 1; i < 16; ++i) m = fmaxf(m, v[i]);
#pragma unroll
    for (int off = 32; off > 0; off >>= 1) m = fmaxf(m, __shfl_xor(m, off));

    __shared__ float redm[4], reds[4];
    const int wid = tid >> 6;
    if ((tid & 63) == 0) redm[wid] = m;
    __syncthreads();
    m = fmaxf(fmaxf(redm[0], redm[1]), fmaxf(redm[2], redm[3]));

    float e[16], s = 0.f;
#pragma unroll
    for (int i = 0; i < 16; ++i) { e[i] = __expf(v[i] - m); s += e[i]; }
#pragma unroll
    for (int off = 32; off > 0; off >>= 1) s += __shfl_xor(s, off);
    if ((tid & 63) == 0) reds[wid] = s;
    __syncthreads();
    s = reds[0] + reds[1] + reds[2] + reds[3];
    const float inv = 1.0f / s;                    // s >= 1 always

#pragma unroll
    for (int i = 0; i < 8; ++i) {
        h0[i] = (_Float16)(e[i] * inv);
        h1[i] = (_Float16)(e[8 + i] * inv);
    }
    *(half8*)(p + tid * 16)     = h0;
    *(half8*)(p + tid * 16 + 8) = h1;
}

// ---------------------------------------------------------------------------
// 4) PV: y[b,q,d] = sum_k P[b,q,k]*Vt[b,d,k] + x[b,q,d]; y -> d_out (fp32).
//    grid (32,8,4). Row norms recomputed later by normalize_kernel.
// ---------------------------------------------------------------------------
__global__ __launch_bounds__(256) void pv_kernel(
    const u16* __restrict__ P, const u16* __restrict__ Vt,
    const float* __restrict__ x, float* __restrict__ y)
{
    __shared__ __align__(16) u16 As[128 * BK];
    __shared__ __align__(16) u16 Bs[128 * BK];
    const int b = blockIdx.z;
    const int tile_m = blockIdx.x * 128;           // query tile
    const int tile_n = blockIdx.y * 128;           // d tile
    const u16* Ab = P  + (size_t)b * S * S + (size_t)tile_m * S;
    const u16* Bv = Vt + (size_t)b * D * S + (size_t)tile_n * S;

    f32x16 acc[2][2];
#pragma unroll
    for (int i = 0; i < 2; ++i)
#pragma unroll
        for (int j = 0; j < 2; ++j) acc[i][j] = (f32x16)0.0f;

    gemm_nt_async(Ab, Bv, S, As, Bs, acc);

    const int tid = threadIdx.x, lane = tid & 63, wid = tid >> 6;
    const int l31 = lane & 31;
    const int wm = (wid & 1) * 64, wn = (wid >> 1) * 64;

#pragma unroll
    for (int im = 0; im < 2; ++im)
#pragma unroll
        for (int in = 0; in < 2; ++in)
#pragma unroll
            for (int r = 0; r < 16; ++r) {
                const int row = tile_m + wm + im * 32 + cd_row(r, lane);
                const size_t base = ((size_t)b * S + row) * D;
                const int col = tile_n + wn + in * 32 + l31;
                y[base + col] = acc[im][in][r] + x[base + col];
            }
}

// ---------------------------------------------------------------------------
// 5) normalize rows of y (fp32) in place: block per row, 256 thr x float4.
// ---------------------------------------------------------------------------
__global__ __launch_bounds__(256) void normalize_kernel(float* __restrict__ y)
{
    const size_t row = blockIdx.x;
    const int tid = threadIdx.x;
    float4* p = (float4*)(y + row * D) + tid;

    float4 v = *p;
    float ss = v.x * v.x + v.y * v.y + v.z * v.z + v.w * v.w;
#pragma unroll
    for (int off = 32; off > 0; off >>= 1) ss += __shfl_xor(ss, off);

    __shared__ float red[4];
    const int wid = tid >> 6;
    if ((tid & 63) == 0) red[wid] = ss;
    __syncthreads();
    const float inv = rsqrtf(red[0] + red[1] + red[2] + red[3]);

    v.x *= inv; v.y *= inv; v.z *= inv; v.w *= inv;
    *p = v;
}

// ---------------------------------------------------------------------------
// Workspace layout (224 MiB total, aggressive aliasing):
//   [0,32M)     Q   (fp16)
//   [32M,64M)   Kb  (fp16)
//   [64M,96M)   Vt  (fp16)   -- written directly by qkv (transposed epilogue)
//   [96M,224M)  P   (fp16)   -- x16 in [96M,128M) and W16 (6 MiB) in
//                               [218M,224M) until scores overwrites with P
// Lifetimes: cvt writes x16,W16 -> qkv reads x16,W16, writes Q,Kb,Vt ->
// scores reads Q,Kb, writes P (over dead x16/W16) -> softmax -> pv -> norm.
// ---------------------------------------------------------------------------
extern "C" void kernel_launch(void* const* d_in, const int* in_sizes, int n_in,
                              void* d_out, int out_size, void* d_ws, size_t ws_size,
                              hipStream_t stream) {
    const float* x  = (const float*)d_in[0];
    const float* Wq = (const float*)d_in[1];
    const float* Wk = (const float*)d_in[2];
    const float* Wv = (const float*)d_in[3];
    float* out = (float*)d_out;

    char* ws = (char*)d_ws;
    const size_t MB = 1ull << 20;
    u16* Q   = (u16*)(ws);
    u16* Kb  = (u16*)(ws + 32 * MB);
    u16* Vt  = (u16*)(ws + 64 * MB);
    u16* P   = (u16*)(ws + 96 * MB);
    u16* x16 = P;                                  // alias: dead before P written
    u16* W16 = (u16*)(ws + 218 * MB);              // alias into P tail: dead before
                                                   // scores writes there

    dim3 blk(256);
    cvt_kernel <<<dim3(NB * S * D / 8 / 256), blk, 0, stream>>>(x,  x16, NB * S * D / 8);
    cvt_kernel <<<dim3(D * D / 8 / 256), blk, 0, stream>>>(Wq, W16,                     D * D / 8);
    cvt_kernel <<<dim3(D * D / 8 / 256), blk, 0, stream>>>(Wk, W16 + (size_t)D * D,     D * D / 8);
    cvt_kernel <<<dim3(D * D / 8 / 256), blk, 0, stream>>>(Wv, W16 + (size_t)2 * D * D, D * D / 8);

    qkv_kernel    <<<dim3(NB * S / 128, D / 128, 3), blk, 0, stream>>>(x16, W16, Q, Kb, Vt);
    scores_kernel <<<dim3(S / 128, S / 128, NB), blk, 0, stream>>>(Q, Kb, P);
    softmax_kernel<<<dim3(NB * S), blk, 0, stream>>>(P);
    pv_kernel     <<<dim3(S / 128, D / 128, NB), blk, 0, stream>>>(P, Vt, x, out);
    normalize_kernel<<<dim3(NB * S), blk, 0, stream>>>(out);
}